// Round 9
// baseline (869.017 us; speedup 1.0000x reference)
//
#include <hip/hip_runtime.h>

// 3-layer GCN 2->16->16->1, N=250k, E=4M.
// R9: aggregation = massive-TLP scatter atomics (R0 structure) over the
// dst-bucket-ordered ent stream (R5 binning). Reads: coalesced ent + random
// rows (latency hidden by ~32 waves/CU; atomics are fire-and-forget).
// Writes: dst-ordered -> atomics merge in a moving L2 window (~16KB/block).
// Per-layer transform epilogues are flat kernels; transforms commuted around
// the linear aggregation: layer1 aggregates 8B dx rows, layer2 16-wide dh1,
// layer3 scalars.

constexpr int K   = 977;   // ceil(250000/256) dst buckets
constexpr int NPW = 256;   // nodes per bucket
constexpr int G   = 256;   // binning blocks
constexpr int F   = 16;

// ---- binning by dst bucket (R5, proven) -------------------------------------

__global__ __launch_bounds__(1024) void k_bcount(const int* __restrict__ dst,
        int* __restrict__ bcount, int E, int chunk) {
    __shared__ int h[K];
    for (int k = threadIdx.x; k < K; k += 1024) h[k] = 0;
    __syncthreads();
    int beg = blockIdx.x * chunk, end = min(beg + chunk, E);
    for (int i = beg + threadIdx.x; i < end; i += 1024) {
        int d = __builtin_nontemporal_load(&dst[i]);
        atomicAdd(&h[d >> 8], 1);
    }
    __syncthreads();
    for (int k = threadIdx.x; k < K; k += 1024)
        bcount[blockIdx.x * K + k] = h[k];   // block-major, coalesced
}

__global__ __launch_bounds__(1024) void k_scan(int* __restrict__ bcount,
        int* __restrict__ colbase, int E) {
    __shared__ int tot[1024];
    int k = threadIdx.x;
    int s = 0;
    if (k < K) for (int b = 0; b < G; ++b) s += bcount[b * K + k];
    tot[k] = s;
    __syncthreads();
    for (int off = 1; off < 1024; off <<= 1) {
        int t = (k >= off) ? tot[k - off] : 0;
        __syncthreads();
        tot[k] += t;
        __syncthreads();
    }
    if (k < K) {
        int run = tot[k] - s;
        colbase[k] = run;
        for (int b = 0; b < G; ++b) {
            int t = bcount[b * K + k];
            bcount[b * K + k] = run;
            run += t;
        }
    }
    if (k == 0) colbase[K] = E;
}

// ent[pos] = (src << 8) | (dst & 255); bucket implicit from position.
__global__ __launch_bounds__(1024) void k_bfill(const int* __restrict__ src,
        const int* __restrict__ dst, const int* __restrict__ base,
        int* __restrict__ ent, int E, int chunk) {
    __shared__ int cur[K];
    for (int k = threadIdx.x; k < K; k += 1024)
        cur[k] = base[blockIdx.x * K + k];
    __syncthreads();
    int beg = blockIdx.x * chunk, end = min(beg + chunk, E);
    for (int i = beg + threadIdx.x; i < end; i += 1024) {
        int d = __builtin_nontemporal_load(&dst[i]);
        int s = __builtin_nontemporal_load(&src[i]);
        int pos = atomicAdd(&cur[d >> 8], 1);
        ent[pos] = (s << 8) | (d & 255);
    }
}

// ---- per-bucket degree + pre-scaled 2-wide input ----------------------------

__global__ __launch_bounds__(256) void k_prep(const int* __restrict__ ent,
        const int* __restrict__ colbase, const float* __restrict__ x,
        float* __restrict__ dinv, float* __restrict__ dx, int n) {
    __shared__ int h[NPW];
    h[threadIdx.x] = 0;
    __syncthreads();
    int beg = colbase[blockIdx.x], end = colbase[blockIdx.x + 1];
    for (int e = beg + threadIdx.x; e < end; e += 256)
        atomicAdd(&h[ent[e] & 255], 1);
    __syncthreads();
    int i = (blockIdx.x << 8) + threadIdx.x;
    if (i < n) {
        float di = rsqrtf((float)h[threadIdx.x] + 1.0f);
        dinv[i] = di;
        float2 xv = reinterpret_cast<const float2*>(x)[i];
        reinterpret_cast<float2*>(dx)[i] = make_float2(di * xv.x, di * xv.y);
    }
}

// ---- layer 1 scatter: agg2[dst] += dx[src] (1 thread/edge, 8 segs/bucket) ---

__global__ __launch_bounds__(256) void k_scat2(const int* __restrict__ ent,
        const int* __restrict__ colbase, const float* __restrict__ dx,
        float* __restrict__ agg2) {
    int k = blockIdx.x >> 3, seg = blockIdx.x & 7;
    int beg = colbase[k], end = colbase[k + 1];
    for (int e = beg + seg * 256 + threadIdx.x; e < end; e += 8 * 256) {
        int v = ent[e];
        float2 a = reinterpret_cast<const float2*>(dx)[v >> 8];
        int d = (k << 8) + (v & 255);
        atomicAdd(&agg2[d * 2 + 0], a.x);
        atomicAdd(&agg2[d * 2 + 1], a.y);
    }
}

// layer1 epilogue: dh1[i] = dinv*relu([dinv*(agg2+dx_self)]@W1 + b1)
__global__ __launch_bounds__(256) void k_l1b(const float* __restrict__ agg2,
        const float* __restrict__ dx, const float* __restrict__ dinv,
        const float* __restrict__ W1, const float* __restrict__ b1,
        float* __restrict__ dh1, int n) {
    __shared__ float sW[32];
    __shared__ float sb[16];
    if (threadIdx.x < 32) sW[threadIdx.x] = W1[threadIdx.x];
    if (threadIdx.x >= 32 && threadIdx.x < 48) sb[threadIdx.x - 32] = b1[threadIdx.x - 32];
    __syncthreads();
    int i = blockIdx.x * 256 + threadIdx.x;
    if (i >= n) return;
    float di = dinv[i];
    float2 ds = reinterpret_cast<const float2*>(dx)[i];
    float2 ag = reinterpret_cast<const float2*>(agg2)[i];
    float a0 = di * (ag.x + ds.x);
    float a1 = di * (ag.y + ds.y);
    float4* orow = reinterpret_cast<float4*>(dh1 + (size_t)i * F);
#pragma unroll
    for (int q = 0; q < 4; ++q) {
        float4 o;
        o.x = di * fmaxf(a0 * sW[4*q+0] + a1 * sW[16 + 4*q+0] + sb[4*q+0], 0.0f);
        o.y = di * fmaxf(a0 * sW[4*q+1] + a1 * sW[16 + 4*q+1] + sb[4*q+1], 0.0f);
        o.z = di * fmaxf(a0 * sW[4*q+2] + a1 * sW[16 + 4*q+2] + sb[4*q+2], 0.0f);
        o.w = di * fmaxf(a0 * sW[4*q+3] + a1 * sW[16 + 4*q+3] + sb[4*q+3], 0.0f);
        orow[q] = o;
    }
}

// ---- layer 2 scatter: agg16[dst][:] += dh1[src][:] (16 lanes/edge, 16 segs) -

__global__ __launch_bounds__(256) void k_scat16(const int* __restrict__ ent,
        const int* __restrict__ colbase, const float* __restrict__ dh1,
        float* __restrict__ agg16) {
    int k = blockIdx.x >> 4, seg = blockIdx.x & 15;
    int beg = colbase[k], end = colbase[k + 1];
    int j = threadIdx.x & 15;
    for (int e = beg + seg * 16 + (threadIdx.x >> 4); e < end; e += 16 * 16) {
        int v = ent[e];
        float val = dh1[(size_t)(v >> 8) * F + j];
        atomicAdd(&agg16[((size_t)(k << 8) + (v & 255)) * F + j], val);
    }
}

// layer2 epilogue: a = di*(agg16+dh1_self); h2 = relu(a@W2+b2); dxw3 = di*(h2.W3)
__global__ __launch_bounds__(256) void k_l2b(const float* __restrict__ agg16,
        const float* __restrict__ dh1, const float* __restrict__ dinv,
        const float* __restrict__ W2, const float* __restrict__ b2,
        const float* __restrict__ W3, float* __restrict__ dxw3, int n) {
    __shared__ float sW2[256];
    __shared__ float sW3[16];
    __shared__ float sb[16];
    sW2[threadIdx.x] = W2[threadIdx.x];
    if (threadIdx.x < 16) sW3[threadIdx.x] = W3[threadIdx.x];
    else if (threadIdx.x < 32) sb[threadIdx.x - 16] = b2[threadIdx.x - 16];
    __syncthreads();
    int i = blockIdx.x * 256 + threadIdx.x;
    if (i >= n) return;
    float di = dinv[i];
    const float* ag = agg16 + (size_t)i * F;
    const float* dh = dh1 + (size_t)i * F;
    float a[16];
#pragma unroll
    for (int q = 0; q < 16; ++q) a[q] = di * (ag[q] + dh[q]);
    float sum = 0.0f;
#pragma unroll
    for (int c = 0; c < 16; ++c) {
        float h = sb[c];
#pragma unroll
        for (int q = 0; q < 16; ++q) h += a[q] * sW2[q * 16 + c];
        sum += fmaxf(h, 0.0f) * sW3[c];
    }
    dxw3[i] = di * sum;
}

// ---- layer 3 scatter + epilogue ---------------------------------------------

__global__ __launch_bounds__(256) void k_scat1(const int* __restrict__ ent,
        const int* __restrict__ colbase, const float* __restrict__ dxw3,
        float* __restrict__ agg1) {
    int k = blockIdx.x >> 3, seg = blockIdx.x & 7;
    int beg = colbase[k], end = colbase[k + 1];
    for (int e = beg + seg * 256 + threadIdx.x; e < end; e += 8 * 256) {
        int v = ent[e];
        float s = dxw3[v >> 8];
        atomicAdd(&agg1[(k << 8) + (v & 255)], s);
    }
}

__global__ __launch_bounds__(256) void k_outb(const float* __restrict__ agg1,
        const float* __restrict__ dxw3, const float* __restrict__ dinv,
        const float* __restrict__ b3, float* __restrict__ out, int n) {
    int i = blockIdx.x * 256 + threadIdx.x;
    if (i < n) out[i] = dinv[i] * (agg1[i] + dxw3[i]) + b3[0];
}

// ---- launch -------------------------------------------------------------------

extern "C" void kernel_launch(void* const* d_in, const int* in_sizes, int n_in,
                              void* d_out, int out_size, void* d_ws, size_t ws_size,
                              hipStream_t stream) {
    const float* x  = (const float*)d_in[0];
    const int*   ei = (const int*)d_in[1];
    const float* W1 = (const float*)d_in[2];
    const float* b1 = (const float*)d_in[3];
    const float* W2 = (const float*)d_in[4];
    const float* b2 = (const float*)d_in[5];
    const float* W3 = (const float*)d_in[6];
    const float* b3 = (const float*)d_in[7];

    const int n = in_sizes[0] / 2;   // [n,2]
    const int E = in_sizes[1] / 2;   // [2,E]
    const int* src = ei;
    const int* dst = ei + E;

    char* w = (char*)d_ws;
    int*   ent     = (int*)w;                 w += (size_t)E * 4;          // 16MB
    int*   bcount  = (int*)w;                 w += (size_t)G * K * 4;      // ~1MB
    int*   colbase = (int*)w;                 w += (size_t)(K + 1) * 4;
    w = (char*)(((uintptr_t)w + 15) & ~(uintptr_t)15);
    float* dinv    = (float*)w;               w += (size_t)n * 4;          // 1MB
    float* dx      = (float*)w;               w += (size_t)n * 2 * 4;      // 2MB
    float* dh1     = (float*)w;               w += (size_t)n * F * 4;      // 16MB
    // agg pool (16MB): agg2 (n*8B) -> agg16 (n*64B) -> agg1 (n*4B), sequential lives
    float* aggp    = (float*)w;               w += (size_t)n * F * 4;      // 16MB
    float* dxw3    = (float*)w;               w += (size_t)n * 4;          // 1MB
    float* agg2  = aggp;
    float* agg16 = aggp;
    float* agg1  = aggp;
    float* out   = (float*)d_out;

    const int chunk = (E + G - 1) / G;
    const int gridN = (n + 255) / 256;

    // binning
    k_bcount<<<G, 1024, 0, stream>>>(dst, bcount, E, chunk);
    k_scan  <<<1, 1024, 0, stream>>>(bcount, colbase, E);
    k_bfill <<<G, 1024, 0, stream>>>(src, dst, bcount, ent, E, chunk);

    // degree + pre-scaled input
    k_prep<<<K, 256, 0, stream>>>(ent, colbase, x, dinv, dx, n);

    // layer 1
    hipMemsetAsync(agg2, 0, (size_t)n * 2 * 4, stream);
    k_scat2<<<K * 8, 256, 0, stream>>>(ent, colbase, dx, agg2);
    k_l1b<<<gridN, 256, 0, stream>>>(agg2, dx, dinv, W1, b1, dh1, n);

    // layer 2
    hipMemsetAsync(agg16, 0, (size_t)n * F * 4, stream);
    k_scat16<<<K * 16, 256, 0, stream>>>(ent, colbase, dh1, agg16);
    k_l2b<<<gridN, 256, 0, stream>>>(agg16, dh1, dinv, W2, b2, W3, dxw3, n);

    // layer 3
    hipMemsetAsync(agg1, 0, (size_t)n * 4, stream);
    k_scat1<<<K * 8, 256, 0, stream>>>(ent, colbase, dxw3, agg1);
    k_outb<<<gridN, 256, 0, stream>>>(agg1, dxw3, dinv, b3, out, n);
}

// Round 10
// 583.383 us; speedup vs baseline: 1.4896x; 1.4896x over previous
//
#include <hip/hip_runtime.h>

// 3-layer GCN 2->16->16->1, N=250k, E=4M.
// R10: bins = (dst_chunk c [256 nodes], src_group g [8 groups of 31250]).
// Layer2: one block per bin, blockIdx%8==g -> block lands on XCD g whose L2
// holds slice g of dh1 (R8-proven: gathers become L2 hits, FETCH 208->16MB).
// Accumulator: 256x17 LDS tile (17.4KB -> 8 blocks/CU) + coalesced atomic
// flush (32M atomics total - the only global float atomics left; measured
// wall ~4B HBM partial-write per atomic). Scan parallelized across blocks
// (old single-block k_scan was a hidden serial bottleneck).
// Transforms commuted around the linear aggregation: layer1 aggregates 8B dx
// rows, layer2 16-wide dh1, layer3 scalars; flat/fused epilogues.

constexpr int NPW = 256;            // dst nodes per chunk
constexpr int K   = 977;            // ceil(250000/256) chunks
constexpr int B   = K * 8;          // 7816 bins
constexpr int G   = 256;            // binning blocks
constexpr int F   = 16;

// ---- binning by (dst chunk, src group) --------------------------------------

__global__ __launch_bounds__(1024) void k_bcount(const int* __restrict__ src,
        const int* __restrict__ dst, int* __restrict__ bcount,
        int E, int chunk, int npg) {
    __shared__ int h[B];
    for (int k = threadIdx.x; k < B; k += 1024) h[k] = 0;
    __syncthreads();
    int beg = blockIdx.x * chunk, end = min(beg + chunk, E);
    for (int i = beg + threadIdx.x; i < end; i += 1024) {
        int s = __builtin_nontemporal_load(&src[i]);
        int d = __builtin_nontemporal_load(&dst[i]);
        atomicAdd(&h[(d >> 8) * 8 + s / npg], 1);
    }
    __syncthreads();
    for (int k = threadIdx.x; k < B; k += 1024)
        bcount[blockIdx.x * B + k] = h[k];     // block-major, coalesced
}

// bin totals (parallel, coalesced: consecutive threads = consecutive bins)
__global__ __launch_bounds__(256) void k_colsum(const int* __restrict__ bcount,
        int* __restrict__ tot) {
    int k = blockIdx.x * 256 + threadIdx.x;
    if (k >= B) return;
    int s = 0;
    for (int b = 0; b < G; ++b) s += bcount[b * B + k];
    tot[k] = s;
}

// exclusive scan of tot[B] -> colbase (single block, only B elements)
__global__ __launch_bounds__(1024) void k_binscan(const int* __restrict__ tot,
        int* __restrict__ colbase, int E) {
    __shared__ int cs[1024];
    int t = threadIdx.x;
    int v[8];
    int mytot = 0;
#pragma unroll
    for (int p = 0; p < 8; ++p) {
        int k = t * 8 + p;
        v[p] = (k < B) ? tot[k] : 0;
        mytot += v[p];
    }
    cs[t] = mytot;
    __syncthreads();
    for (int off = 1; off < 1024; off <<= 1) {
        int x = (t >= off) ? cs[t - off] : 0;
        __syncthreads();
        cs[t] += x;
        __syncthreads();
    }
    int run = cs[t] - mytot;
#pragma unroll
    for (int p = 0; p < 8; ++p) {
        int k = t * 8 + p;
        if (k < B) colbase[k] = run;
        run += v[p];
    }
    if (t == 1023) colbase[B] = E;
}

// rewrite bcount in place as per-(block,bin) exclusive bases (parallel)
__global__ __launch_bounds__(256) void k_rebase(int* __restrict__ bcount,
        const int* __restrict__ colbase) {
    int k = blockIdx.x * 256 + threadIdx.x;
    if (k >= B) return;
    int run = colbase[k];
    for (int b = 0; b < G; ++b) {
        int t = bcount[b * B + k];
        bcount[b * B + k] = run;
        run += t;
    }
}

// ent[pos] = (src_local << 8) | dst_local   (15 + 8 bits)
__global__ __launch_bounds__(1024) void k_bfill(const int* __restrict__ src,
        const int* __restrict__ dst, const int* __restrict__ base,
        int* __restrict__ ent, int E, int chunk, int npg) {
    __shared__ int cur[B];
    for (int k = threadIdx.x; k < B; k += 1024)
        cur[k] = base[blockIdx.x * B + k];
    __syncthreads();
    int beg = blockIdx.x * chunk, end = min(beg + chunk, E);
    for (int i = beg + threadIdx.x; i < end; i += 1024) {
        int s = __builtin_nontemporal_load(&src[i]);
        int d = __builtin_nontemporal_load(&dst[i]);
        int g = s / npg;
        int pos = atomicAdd(&cur[(d >> 8) * 8 + g], 1);
        ent[pos] = ((s - g * npg) << 8) | (d & 255);
    }
}

// ---- per-chunk degree + pre-scaled 2-wide input ------------------------------

__global__ __launch_bounds__(256) void k_prep(const int* __restrict__ ent,
        const int* __restrict__ colbase, const float* __restrict__ x,
        float* __restrict__ dinv, float* __restrict__ dx, int n) {
    __shared__ int h[NPW];
    h[threadIdx.x] = 0;
    __syncthreads();
    int beg = colbase[blockIdx.x * 8], end = colbase[blockIdx.x * 8 + 8];
    for (int e = beg + threadIdx.x; e < end; e += 256)
        atomicAdd(&h[ent[e] & 255], 1);
    __syncthreads();
    int i = (blockIdx.x << 8) + threadIdx.x;
    if (i < n) {
        float di = rsqrtf((float)h[threadIdx.x] + 1.0f);
        dinv[i] = di;
        float2 xv = reinterpret_cast<const float2*>(x)[i];
        reinterpret_cast<float2*>(dx)[i] = make_float2(di * xv.x, di * xv.y);
    }
}

// ---- layer 1: aggregate 2-wide dx in LDS; fused (2->16) W1+b1+relu ----------

__global__ __launch_bounds__(512) void k_layer1(const int* __restrict__ ent,
        const int* __restrict__ colbase, const float* __restrict__ dinv,
        const float* __restrict__ dx, const float* __restrict__ W1,
        const float* __restrict__ b1, float* __restrict__ dh1, int n, int npg) {
    __shared__ float acc[NPW * 2];
    __shared__ float sW[32];
    __shared__ float sb[16];
    if (threadIdx.x < 32) sW[threadIdx.x] = W1[threadIdx.x];
    if (threadIdx.x >= 32 && threadIdx.x < 48) sb[threadIdx.x - 32] = b1[threadIdx.x - 32];
    for (int t = threadIdx.x; t < NPW * 2; t += 512) acc[t] = 0.0f;
    __syncthreads();
    for (int g = 0; g < 8; ++g) {
        int sbase = g * npg;
        int beg = colbase[blockIdx.x * 8 + g], end = colbase[blockIdx.x * 8 + g + 1];
        int e = beg + threadIdx.x;
        for (; e + 512 < end; e += 1024) {
            int v0 = ent[e], v1 = ent[e + 512];
            float2 a0 = reinterpret_cast<const float2*>(dx)[sbase + (v0 >> 8)];
            float2 a1 = reinterpret_cast<const float2*>(dx)[sbase + (v1 >> 8)];
            atomicAdd(&acc[(v0 & 255) * 2 + 0], a0.x);
            atomicAdd(&acc[(v0 & 255) * 2 + 1], a0.y);
            atomicAdd(&acc[(v1 & 255) * 2 + 0], a1.x);
            atomicAdd(&acc[(v1 & 255) * 2 + 1], a1.y);
        }
        if (e < end) {
            int v = ent[e];
            float2 a = reinterpret_cast<const float2*>(dx)[sbase + (v >> 8)];
            atomicAdd(&acc[(v & 255) * 2 + 0], a.x);
            atomicAdd(&acc[(v & 255) * 2 + 1], a.y);
        }
    }
    __syncthreads();
    int r = threadIdx.x;
    if (r < NPW) {
        int i = (blockIdx.x << 8) + r;
        if (i < n) {
            float di = dinv[i];
            float2 ds = reinterpret_cast<const float2*>(dx)[i];
            float a0 = di * (acc[r * 2 + 0] + ds.x);
            float a1 = di * (acc[r * 2 + 1] + ds.y);
            float4* orow = reinterpret_cast<float4*>(dh1 + (size_t)i * F);
#pragma unroll
            for (int q = 0; q < 4; ++q) {
                float4 o;
                o.x = di * fmaxf(a0 * sW[4*q+0] + a1 * sW[16 + 4*q+0] + sb[4*q+0], 0.0f);
                o.y = di * fmaxf(a0 * sW[4*q+1] + a1 * sW[16 + 4*q+1] + sb[4*q+1], 0.0f);
                o.z = di * fmaxf(a0 * sW[4*q+2] + a1 * sW[16 + 4*q+2] + sb[4*q+2], 0.0f);
                o.w = di * fmaxf(a0 * sW[4*q+3] + a1 * sW[16 + 4*q+3] + sb[4*q+3], 0.0f);
                orow[q] = o;
            }
        }
    }
}

// ---- layer 2 scatter: one block per (chunk,group) bin; blockIdx%8 = group ---
// Gathers dh1 rows from the XCD-local 2MB slice, accumulates in a 256x17 LDS
// tile (17.4KB -> 8 blocks/CU), flushes coalesced atomics into agg16.

__global__ __launch_bounds__(256) void k_l2s(const int* __restrict__ ent,
        const int* __restrict__ colbase, const float* __restrict__ dh1,
        float* __restrict__ agg16, int npg) {
    __shared__ float acc[NPW * 17];      // stride 17: bank-spread
    for (int t = threadIdx.x; t < NPW * 17; t += 256) acc[t] = 0.0f;
    __syncthreads();
    int c = blockIdx.x >> 3, g = blockIdx.x & 7;
    int sbase = g * npg;
    int beg = colbase[blockIdx.x], end = colbase[blockIdx.x + 1];
    int q4 = (threadIdx.x & 3) * 4;      // feature quad 0/4/8/12
    int e = beg + (threadIdx.x >> 2);    // 64 edge slots
    for (; e + 64 < end; e += 128) {
        int v0 = ent[e], v1 = ent[e + 64];
        float4 r0 = *reinterpret_cast<const float4*>(dh1 + (size_t)(sbase + (v0 >> 8)) * F + q4);
        float4 r1 = *reinterpret_cast<const float4*>(dh1 + (size_t)(sbase + (v1 >> 8)) * F + q4);
        int a0 = (v0 & 255) * 17 + q4;
        int a1 = (v1 & 255) * 17 + q4;
        atomicAdd(&acc[a0 + 0], r0.x); atomicAdd(&acc[a0 + 1], r0.y);
        atomicAdd(&acc[a0 + 2], r0.z); atomicAdd(&acc[a0 + 3], r0.w);
        atomicAdd(&acc[a1 + 0], r1.x); atomicAdd(&acc[a1 + 1], r1.y);
        atomicAdd(&acc[a1 + 2], r1.z); atomicAdd(&acc[a1 + 3], r1.w);
    }
    if (e < end) {
        int v = ent[e];
        float4 r = *reinterpret_cast<const float4*>(dh1 + (size_t)(sbase + (v >> 8)) * F + q4);
        int a0 = (v & 255) * 17 + q4;
        atomicAdd(&acc[a0 + 0], r.x); atomicAdd(&acc[a0 + 1], r.y);
        atomicAdd(&acc[a0 + 2], r.z); atomicAdd(&acc[a0 + 3], r.w);
    }
    __syncthreads();
    float* aggc = agg16 + (size_t)c * NPW * F;    // agg16 padded to K*256*16
    for (int t = threadIdx.x; t < NPW * F; t += 256)
        atomicAdd(&aggc[t], acc[(t >> 4) * 17 + (t & 15)]);
}

// layer2 epilogue: a = di*(agg16+dh1_self); h2 = relu(a@W2+b2); dxw3 = di*(h2.W3)
__global__ __launch_bounds__(256) void k_l2b(const float* __restrict__ agg16,
        const float* __restrict__ dh1, const float* __restrict__ dinv,
        const float* __restrict__ W2, const float* __restrict__ b2,
        const float* __restrict__ W3, float* __restrict__ dxw3, int n) {
    __shared__ float sW2[256];
    __shared__ float sW3[16];
    __shared__ float sb[16];
    sW2[threadIdx.x] = W2[threadIdx.x];
    if (threadIdx.x < 16) sW3[threadIdx.x] = W3[threadIdx.x];
    else if (threadIdx.x < 32) sb[threadIdx.x - 16] = b2[threadIdx.x - 16];
    __syncthreads();
    int i = blockIdx.x * 256 + threadIdx.x;
    if (i >= n) return;
    float di = dinv[i];
    const float* ag = agg16 + (size_t)i * F;
    const float* dh = dh1 + (size_t)i * F;
    float a[16];
#pragma unroll
    for (int q = 0; q < 16; ++q) a[q] = di * (ag[q] + dh[q]);
    float sum = 0.0f;
#pragma unroll
    for (int c = 0; c < 16; ++c) {
        float h = sb[c];
#pragma unroll
        for (int q = 0; q < 16; ++q) h += a[q] * sW2[q * 16 + c];
        sum += fmaxf(h, 0.0f) * sW3[c];
    }
    dxw3[i] = di * sum;
}

// ---- layer 3: scalar LDS aggregation + fused output --------------------------

__global__ __launch_bounds__(512) void k_out(const int* __restrict__ ent,
        const int* __restrict__ colbase, const float* __restrict__ dinv,
        const float* __restrict__ dxw3, const float* __restrict__ b3,
        float* __restrict__ out, int n, int npg) {
    __shared__ float acc[NPW];
    for (int t = threadIdx.x; t < NPW; t += 512) acc[t] = 0.0f;
    __syncthreads();
    for (int g = 0; g < 8; ++g) {
        int sbase = g * npg;
        int beg = colbase[blockIdx.x * 8 + g], end = colbase[blockIdx.x * 8 + g + 1];
        int e = beg + threadIdx.x;
        for (; e + 512 < end; e += 1024) {
            int v0 = ent[e], v1 = ent[e + 512];
            float s0 = dxw3[sbase + (v0 >> 8)];
            float s1 = dxw3[sbase + (v1 >> 8)];
            atomicAdd(&acc[v0 & 255], s0);
            atomicAdd(&acc[v1 & 255], s1);
        }
        if (e < end) {
            int v = ent[e];
            atomicAdd(&acc[v & 255], dxw3[sbase + (v >> 8)]);
        }
    }
    __syncthreads();
    int r = threadIdx.x;
    if (r < NPW) {
        int i = (blockIdx.x << 8) + r;
        if (i < n) out[i] = dinv[i] * (acc[r] + dxw3[i]) + b3[0];
    }
}

// ---- launch -------------------------------------------------------------------

extern "C" void kernel_launch(void* const* d_in, const int* in_sizes, int n_in,
                              void* d_out, int out_size, void* d_ws, size_t ws_size,
                              hipStream_t stream) {
    const float* x  = (const float*)d_in[0];
    const int*   ei = (const int*)d_in[1];
    const float* W1 = (const float*)d_in[2];
    const float* b1 = (const float*)d_in[3];
    const float* W2 = (const float*)d_in[4];
    const float* b2 = (const float*)d_in[5];
    const float* W3 = (const float*)d_in[6];
    const float* b3 = (const float*)d_in[7];

    const int n = in_sizes[0] / 2;            // [n,2] = 250000
    const int E = in_sizes[1] / 2;            // [2,E] = 4000000
    const int* src = ei;
    const int* dst = ei + E;
    const int npg = (n + 7) / 8;              // 31250 src nodes per group

    char* w = (char*)d_ws;
    int*   ent     = (int*)w;                 w += (size_t)E * 4;              // 16MB
    int*   bcount  = (int*)w;                 w += (size_t)G * B * 4;          // 8MB
    int*   tot     = (int*)w;                 w += (size_t)B * 4;
    int*   colbase = (int*)w;                 w += (size_t)(B + 1) * 4;
    w = (char*)(((uintptr_t)w + 15) & ~(uintptr_t)15);
    float* dinv    = (float*)w;               w += (size_t)n * 4;              // 1MB
    float* dx      = (float*)w;               w += (size_t)n * 2 * 4;          // 2MB
    float* dh1     = (float*)w;               w += (size_t)n * F * 4;          // 16MB
    float* agg16   = (float*)w;               w += (size_t)K * NPW * F * 4;    // 16MB (padded)
    float* dxw3    = (float*)w;               w += (size_t)n * 4;              // 1MB
    float* out     = (float*)d_out;

    const int chunk = (E + G - 1) / G;
    const int gridN = (n + 255) / 256;
    const int gridB = (B + 255) / 256;

    // binning by (dst chunk, src group)
    k_bcount <<<G, 1024, 0, stream>>>(src, dst, bcount, E, chunk, npg);
    k_colsum <<<gridB, 256, 0, stream>>>(bcount, tot);
    k_binscan<<<1, 1024, 0, stream>>>(tot, colbase, E);
    k_rebase <<<gridB, 256, 0, stream>>>(bcount, colbase);
    k_bfill  <<<G, 1024, 0, stream>>>(src, dst, bcount, ent, E, chunk, npg);

    // degree + pre-scaled input
    k_prep<<<K, 256, 0, stream>>>(ent, colbase, x, dinv, dx, n);

    // layer 1
    k_layer1<<<K, 512, 0, stream>>>(ent, colbase, dinv, dx, W1, b1, dh1, n, npg);

    // layer 2: XCD-affine gather -> LDS tile -> coalesced atomic flush
    hipMemsetAsync(agg16, 0, (size_t)K * NPW * F * 4, stream);
    k_l2s<<<B, 256, 0, stream>>>(ent, colbase, dh1, agg16, npg);
    k_l2b<<<gridN, 256, 0, stream>>>(agg16, dh1, dinv, W2, b2, W3, dxw3, n);

    // layer 3
    k_out<<<K, 512, 0, stream>>>(ent, colbase, dinv, dxw3, b3, out, n, npg);
}

// Round 11
// 572.021 us; speedup vs baseline: 1.5192x; 1.0199x over previous
//
#include <hip/hip_runtime.h>

// 3-layer GCN 2->16->16->1, N=250k, E=4M.
// R11: bins = (dst_chunk c [256 nodes], src_group g [8 x 31250]). Layer2 is
// ONE block per chunk looping g=0..7: within phase g all concurrent blocks
// read the same 2MB dh1 slice, which fits (replicated) in every XCD's 4MB L2
// -> gathers are L2 hits WITHOUT needing XCD-exclusive ownership. Block owns
// its chunk, so the epilogue (W2+b2+relu+.W3) is fused and written with plain
// coalesced stores: NO global float atomics anywhere in the layer path.
// Layer1 (2-wide) and layer3 (scalar) already use this loop-g structure.

constexpr int NPW = 256;            // dst nodes per chunk
constexpr int K   = 977;            // ceil(250000/256) chunks
constexpr int B   = K * 8;          // 7816 bins
constexpr int G   = 256;            // binning blocks
constexpr int F   = 16;

// ---- binning by (dst chunk, src group) --------------------------------------

__global__ __launch_bounds__(1024) void k_bcount(const int* __restrict__ src,
        const int* __restrict__ dst, int* __restrict__ bcount,
        int E, int chunk, int npg) {
    __shared__ int h[B];
    for (int k = threadIdx.x; k < B; k += 1024) h[k] = 0;
    __syncthreads();
    int beg = blockIdx.x * chunk, end = min(beg + chunk, E);
    for (int i = beg + threadIdx.x; i < end; i += 1024) {
        int s = __builtin_nontemporal_load(&src[i]);
        int d = __builtin_nontemporal_load(&dst[i]);
        atomicAdd(&h[(d >> 8) * 8 + s / npg], 1);
    }
    __syncthreads();
    for (int k = threadIdx.x; k < B; k += 1024)
        bcount[blockIdx.x * B + k] = h[k];     // block-major, coalesced
}

__global__ __launch_bounds__(256) void k_colsum(const int* __restrict__ bcount,
        int* __restrict__ tot) {
    int k = blockIdx.x * 256 + threadIdx.x;
    if (k >= B) return;
    int s = 0;
    for (int b = 0; b < G; ++b) s += bcount[b * B + k];
    tot[k] = s;
}

__global__ __launch_bounds__(1024) void k_binscan(const int* __restrict__ tot,
        int* __restrict__ colbase, int E) {
    __shared__ int cs[1024];
    int t = threadIdx.x;
    int v[8];
    int mytot = 0;
#pragma unroll
    for (int p = 0; p < 8; ++p) {
        int k = t * 8 + p;
        v[p] = (k < B) ? tot[k] : 0;
        mytot += v[p];
    }
    cs[t] = mytot;
    __syncthreads();
    for (int off = 1; off < 1024; off <<= 1) {
        int x = (t >= off) ? cs[t - off] : 0;
        __syncthreads();
        cs[t] += x;
        __syncthreads();
    }
    int run = cs[t] - mytot;
#pragma unroll
    for (int p = 0; p < 8; ++p) {
        int k = t * 8 + p;
        if (k < B) colbase[k] = run;
        run += v[p];
    }
    if (t == 1023) colbase[B] = E;
}

__global__ __launch_bounds__(256) void k_rebase(int* __restrict__ bcount,
        const int* __restrict__ colbase) {
    int k = blockIdx.x * 256 + threadIdx.x;
    if (k >= B) return;
    int run = colbase[k];
    for (int b = 0; b < G; ++b) {
        int t = bcount[b * B + k];
        bcount[b * B + k] = run;
        run += t;
    }
}

// ent[pos] = (src_local << 8) | dst_local   (15 + 8 bits)
__global__ __launch_bounds__(1024) void k_bfill(const int* __restrict__ src,
        const int* __restrict__ dst, const int* __restrict__ base,
        int* __restrict__ ent, int E, int chunk, int npg) {
    __shared__ int cur[B];
    for (int k = threadIdx.x; k < B; k += 1024)
        cur[k] = base[blockIdx.x * B + k];
    __syncthreads();
    int beg = blockIdx.x * chunk, end = min(beg + chunk, E);
    for (int i = beg + threadIdx.x; i < end; i += 1024) {
        int s = __builtin_nontemporal_load(&src[i]);
        int d = __builtin_nontemporal_load(&dst[i]);
        int g = s / npg;
        int pos = atomicAdd(&cur[(d >> 8) * 8 + g], 1);
        ent[pos] = ((s - g * npg) << 8) | (d & 255);
    }
}

// ---- per-chunk degree + pre-scaled 2-wide input ------------------------------

__global__ __launch_bounds__(256) void k_prep(const int* __restrict__ ent,
        const int* __restrict__ colbase, const float* __restrict__ x,
        float* __restrict__ dinv, float* __restrict__ dx, int n) {
    __shared__ int h[NPW];
    h[threadIdx.x] = 0;
    __syncthreads();
    int beg = colbase[blockIdx.x * 8], end = colbase[blockIdx.x * 8 + 8];
    for (int e = beg + threadIdx.x; e < end; e += 256)
        atomicAdd(&h[ent[e] & 255], 1);
    __syncthreads();
    int i = (blockIdx.x << 8) + threadIdx.x;
    if (i < n) {
        float di = rsqrtf((float)h[threadIdx.x] + 1.0f);
        dinv[i] = di;
        float2 xv = reinterpret_cast<const float2*>(x)[i];
        reinterpret_cast<float2*>(dx)[i] = make_float2(di * xv.x, di * xv.y);
    }
}

// ---- layer 1: aggregate 2-wide dx in LDS; fused (2->16) W1+b1+relu ----------

__global__ __launch_bounds__(512) void k_layer1(const int* __restrict__ ent,
        const int* __restrict__ colbase, const float* __restrict__ dinv,
        const float* __restrict__ dx, const float* __restrict__ W1,
        const float* __restrict__ b1, float* __restrict__ dh1, int n, int npg) {
    __shared__ float acc[NPW * 2];
    __shared__ float sW[32];
    __shared__ float sb[16];
    if (threadIdx.x < 32) sW[threadIdx.x] = W1[threadIdx.x];
    if (threadIdx.x >= 32 && threadIdx.x < 48) sb[threadIdx.x - 32] = b1[threadIdx.x - 32];
    for (int t = threadIdx.x; t < NPW * 2; t += 512) acc[t] = 0.0f;
    __syncthreads();
    for (int g = 0; g < 8; ++g) {
        int sbase = g * npg;
        int beg = colbase[blockIdx.x * 8 + g], end = colbase[blockIdx.x * 8 + g + 1];
        int e = beg + threadIdx.x;
        for (; e + 512 < end; e += 1024) {
            int v0 = ent[e], v1 = ent[e + 512];
            float2 a0 = reinterpret_cast<const float2*>(dx)[sbase + (v0 >> 8)];
            float2 a1 = reinterpret_cast<const float2*>(dx)[sbase + (v1 >> 8)];
            atomicAdd(&acc[(v0 & 255) * 2 + 0], a0.x);
            atomicAdd(&acc[(v0 & 255) * 2 + 1], a0.y);
            atomicAdd(&acc[(v1 & 255) * 2 + 0], a1.x);
            atomicAdd(&acc[(v1 & 255) * 2 + 1], a1.y);
        }
        if (e < end) {
            int v = ent[e];
            float2 a = reinterpret_cast<const float2*>(dx)[sbase + (v >> 8)];
            atomicAdd(&acc[(v & 255) * 2 + 0], a.x);
            atomicAdd(&acc[(v & 255) * 2 + 1], a.y);
        }
    }
    __syncthreads();
    int r = threadIdx.x;
    if (r < NPW) {
        int i = (blockIdx.x << 8) + r;
        if (i < n) {
            float di = dinv[i];
            float2 ds = reinterpret_cast<const float2*>(dx)[i];
            float a0 = di * (acc[r * 2 + 0] + ds.x);
            float a1 = di * (acc[r * 2 + 1] + ds.y);
            float4* orow = reinterpret_cast<float4*>(dh1 + (size_t)i * F);
#pragma unroll
            for (int q = 0; q < 4; ++q) {
                float4 o;
                o.x = di * fmaxf(a0 * sW[4*q+0] + a1 * sW[16 + 4*q+0] + sb[4*q+0], 0.0f);
                o.y = di * fmaxf(a0 * sW[4*q+1] + a1 * sW[16 + 4*q+1] + sb[4*q+1], 0.0f);
                o.z = di * fmaxf(a0 * sW[4*q+2] + a1 * sW[16 + 4*q+2] + sb[4*q+2], 0.0f);
                o.w = di * fmaxf(a0 * sW[4*q+3] + a1 * sW[16 + 4*q+3] + sb[4*q+3], 0.0f);
                orow[q] = o;
            }
        }
    }
}

// ---- layer 2: one block per chunk; loop g over src-group segments -----------
// Phase-g working set = slice g of dh1 (2MB) -> L2-resident on every XCD.
// LDS 256x17 accumulator; fused epilogue writes dxw3 with plain stores.

__global__ __launch_bounds__(512) void k_layer2(const int* __restrict__ ent,
        const int* __restrict__ colbase, const float* __restrict__ dinv,
        const float* __restrict__ dh1, const float* __restrict__ W2,
        const float* __restrict__ b2, const float* __restrict__ W3,
        float* __restrict__ dxw3, int n, int npg) {
    __shared__ float acc[NPW * 17];      // stride 17: bank-spread
    __shared__ float sW2[256];
    __shared__ float sW3[16];
    __shared__ float sb[16];
    if (threadIdx.x < 256) sW2[threadIdx.x] = W2[threadIdx.x];
    else if (threadIdx.x < 272) sW3[threadIdx.x - 256] = W3[threadIdx.x - 256];
    else if (threadIdx.x < 288) sb[threadIdx.x - 272] = b2[threadIdx.x - 272];
    for (int t = threadIdx.x; t < NPW * 17; t += 512) acc[t] = 0.0f;
    __syncthreads();
    int q4 = (threadIdx.x & 3) * 4;      // feature quad 0/4/8/12
    int slot = threadIdx.x >> 2;         // 128 edge slots
    for (int g = 0; g < 8; ++g) {
        int sbase = g * npg;
        int beg = colbase[blockIdx.x * 8 + g], end = colbase[blockIdx.x * 8 + g + 1];
        int e = beg + slot;
        for (; e + 128 < end; e += 256) {
            int v0 = ent[e], v1 = ent[e + 128];
            float4 r0 = *reinterpret_cast<const float4*>(dh1 + (size_t)(sbase + (v0 >> 8)) * F + q4);
            float4 r1 = *reinterpret_cast<const float4*>(dh1 + (size_t)(sbase + (v1 >> 8)) * F + q4);
            int a0 = (v0 & 255) * 17 + q4;
            int a1 = (v1 & 255) * 17 + q4;
            atomicAdd(&acc[a0 + 0], r0.x); atomicAdd(&acc[a0 + 1], r0.y);
            atomicAdd(&acc[a0 + 2], r0.z); atomicAdd(&acc[a0 + 3], r0.w);
            atomicAdd(&acc[a1 + 0], r1.x); atomicAdd(&acc[a1 + 1], r1.y);
            atomicAdd(&acc[a1 + 2], r1.z); atomicAdd(&acc[a1 + 3], r1.w);
        }
        if (e < end) {
            int v = ent[e];
            float4 r = *reinterpret_cast<const float4*>(dh1 + (size_t)(sbase + (v >> 8)) * F + q4);
            int a0 = (v & 255) * 17 + q4;
            atomicAdd(&acc[a0 + 0], r.x); atomicAdd(&acc[a0 + 1], r.y);
            atomicAdd(&acc[a0 + 2], r.z); atomicAdd(&acc[a0 + 3], r.w);
        }
    }
    __syncthreads();
    int r = threadIdx.x;
    if (r < NPW) {
        int i = (blockIdx.x << 8) + r;
        if (i < n) {
            float di = dinv[i];
            const float* dh = dh1 + (size_t)i * F;
            float a[16];
#pragma unroll
            for (int q = 0; q < 16; ++q) a[q] = di * (acc[r * 17 + q] + dh[q]);
            float sum = 0.0f;
#pragma unroll
            for (int c = 0; c < 16; ++c) {
                float h = sb[c];
#pragma unroll
                for (int q = 0; q < 16; ++q) h += a[q] * sW2[q * 16 + c];
                sum += fmaxf(h, 0.0f) * sW3[c];
            }
            dxw3[i] = di * sum;
        }
    }
}

// ---- layer 3: scalar LDS aggregation + fused output --------------------------

__global__ __launch_bounds__(512) void k_out(const int* __restrict__ ent,
        const int* __restrict__ colbase, const float* __restrict__ dinv,
        const float* __restrict__ dxw3, const float* __restrict__ b3,
        float* __restrict__ out, int n, int npg) {
    __shared__ float acc[NPW];
    for (int t = threadIdx.x; t < NPW; t += 512) acc[t] = 0.0f;
    __syncthreads();
    for (int g = 0; g < 8; ++g) {
        int sbase = g * npg;
        int beg = colbase[blockIdx.x * 8 + g], end = colbase[blockIdx.x * 8 + g + 1];
        int e = beg + threadIdx.x;
        for (; e + 512 < end; e += 1024) {
            int v0 = ent[e], v1 = ent[e + 512];
            float s0 = dxw3[sbase + (v0 >> 8)];
            float s1 = dxw3[sbase + (v1 >> 8)];
            atomicAdd(&acc[v0 & 255], s0);
            atomicAdd(&acc[v1 & 255], s1);
        }
        if (e < end) {
            int v = ent[e];
            atomicAdd(&acc[v & 255], dxw3[sbase + (v >> 8)]);
        }
    }
    __syncthreads();
    int r = threadIdx.x;
    if (r < NPW) {
        int i = (blockIdx.x << 8) + r;
        if (i < n) out[i] = dinv[i] * (acc[r] + dxw3[i]) + b3[0];
    }
}

// ---- launch -------------------------------------------------------------------

extern "C" void kernel_launch(void* const* d_in, const int* in_sizes, int n_in,
                              void* d_out, int out_size, void* d_ws, size_t ws_size,
                              hipStream_t stream) {
    const float* x  = (const float*)d_in[0];
    const int*   ei = (const int*)d_in[1];
    const float* W1 = (const float*)d_in[2];
    const float* b1 = (const float*)d_in[3];
    const float* W2 = (const float*)d_in[4];
    const float* b2 = (const float*)d_in[5];
    const float* W3 = (const float*)d_in[6];
    const float* b3 = (const float*)d_in[7];

    const int n = in_sizes[0] / 2;            // [n,2] = 250000
    const int E = in_sizes[1] / 2;            // [2,E] = 4000000
    const int* src = ei;
    const int* dst = ei + E;
    const int npg = (n + 7) / 8;              // 31250 src nodes per group

    char* w = (char*)d_ws;
    int*   ent     = (int*)w;                 w += (size_t)E * 4;              // 16MB
    int*   bcount  = (int*)w;                 w += (size_t)G * B * 4;          // 8MB
    int*   tot     = (int*)w;                 w += (size_t)B * 4;
    int*   colbase = (int*)w;                 w += (size_t)(B + 1) * 4;
    w = (char*)(((uintptr_t)w + 15) & ~(uintptr_t)15);
    float* dinv    = (float*)w;               w += (size_t)n * 4;              // 1MB
    float* dx      = (float*)w;               w += (size_t)n * 2 * 4;          // 2MB
    float* dh1     = (float*)w;               w += (size_t)n * F * 4;          // 16MB
    float* dxw3    = (float*)w;               w += (size_t)n * 4;              // 1MB
    float* out     = (float*)d_out;

    const int chunk = (E + G - 1) / G;
    const int gridB = (B + 255) / 256;

    // binning by (dst chunk, src group)
    k_bcount <<<G, 1024, 0, stream>>>(src, dst, bcount, E, chunk, npg);
    k_colsum <<<gridB, 256, 0, stream>>>(bcount, tot);
    k_binscan<<<1, 1024, 0, stream>>>(tot, colbase, E);
    k_rebase <<<gridB, 256, 0, stream>>>(bcount, colbase);
    k_bfill  <<<G, 1024, 0, stream>>>(src, dst, bcount, ent, E, chunk, npg);

    // degree + pre-scaled input
    k_prep<<<K, 256, 0, stream>>>(ent, colbase, x, dinv, dx, n);

    // layers (no global float atomics anywhere)
    k_layer1<<<K, 512, 0, stream>>>(ent, colbase, dinv, dx, W1, b1, dh1, n, npg);
    k_layer2<<<K, 512, 0, stream>>>(ent, colbase, dinv, dh1, W2, b2, W3, dxw3, n, npg);
    k_out   <<<K, 512, 0, stream>>>(ent, colbase, dinv, dxw3, b3, out, n, npg);
}